// Round 8
// baseline (952.631 us; speedup 1.0000x reference)
//
#include <hip/hip_runtime.h>

// VectorQuantizer on MI355X — round 8: single MFMA pass + tile-pair shortlist.
// x: [32768, 64] f32, codebook: [8192, 64] f32.
// out (f32): [0..2097152) quantized, [2097152] loss, [2097153..) indices as floats.
//
// Block = 512 thr (8 waves) x 64 rows; wave w covers cands [w*1024, +1024) as
// 32 tiles of 32 (16 tile-PAIRS). Single MFMA pass stores per-(row, tile-pair)
// maxes of t_k = x.e_k - ||e_k||^2/2 in LDS (f32). Then: block max fold ->
// thr = max - 2.5e-4 -> per-row hot-pair list -> wave-parallel EXACT rescore
// of each hot pair's 64 cands (round-2-validated numpy-replicating numerics,
// first-min tie rule) + gather + loss. No pass-2 recompute, no prep_x
// (bfrag built in-kernel with identical f2bf; sx recomputed with identical
// np_sumsq64_f4). Overflow (>16 hot pairs) -> wave-parallel full scan.

#define NUM_E   8192
#define DIM     64
#define KPAD    80
#define NROWS   32768
#define NELEM   2097152
#define CAP_T   16          // max hot tile-pairs per row
#define TMARGIN 2.5e-4f
#define ROWS_PB 64
#define WAVES   8
#define NT      32          // tiles of 32 cands per wave
#define FLTMAX  3.402823466e+38f

using bf16x8 = __attribute__((ext_vector_type(8))) short;
using f32x16 = __attribute__((ext_vector_type(16))) float;

__device__ __forceinline__ unsigned int f2bf(float f) {
    unsigned int u = __float_as_uint(f);
    return (u + 0x7FFFu + ((u >> 16) & 1u)) >> 16;   // RNE to bf16
}

// numpy pairwise_sum(n=64) of elementwise squares (validated bit-exact r2+).
__device__ __forceinline__ float np_sumsq64_f4(const float4 v[16]) {
    float r0 = __fmul_rn(v[0].x, v[0].x), r1 = __fmul_rn(v[0].y, v[0].y);
    float r2 = __fmul_rn(v[0].z, v[0].z), r3 = __fmul_rn(v[0].w, v[0].w);
    float r4 = __fmul_rn(v[1].x, v[1].x), r5 = __fmul_rn(v[1].y, v[1].y);
    float r6 = __fmul_rn(v[1].z, v[1].z), r7 = __fmul_rn(v[1].w, v[1].w);
#pragma unroll
    for (int t = 1; t < 8; ++t) {
        r0 = __fadd_rn(r0, __fmul_rn(v[2 * t].x, v[2 * t].x));
        r1 = __fadd_rn(r1, __fmul_rn(v[2 * t].y, v[2 * t].y));
        r2 = __fadd_rn(r2, __fmul_rn(v[2 * t].z, v[2 * t].z));
        r3 = __fadd_rn(r3, __fmul_rn(v[2 * t].w, v[2 * t].w));
        r4 = __fadd_rn(r4, __fmul_rn(v[2 * t + 1].x, v[2 * t + 1].x));
        r5 = __fadd_rn(r5, __fmul_rn(v[2 * t + 1].y, v[2 * t + 1].y));
        r6 = __fadd_rn(r6, __fmul_rn(v[2 * t + 1].z, v[2 * t + 1].z));
        r7 = __fadd_rn(r7, __fmul_rn(v[2 * t + 1].w, v[2 * t + 1].w));
    }
    return __fadd_rn(__fadd_rn(__fadd_rn(r0, r1), __fadd_rn(r2, r3)),
                     __fadd_rn(__fadd_rn(r4, r5), __fadd_rn(r6, r7)));
}

__global__ __launch_bounds__(256)
void vq_prep_cb(const float* __restrict__ cb, float* __restrict__ norms,
                unsigned short* __restrict__ ebuf) {
    const int row = blockIdx.x * 256 + threadIdx.x;
    float4 e[16];
    const float4* p = reinterpret_cast<const float4*>(cb + row * DIM);
#pragma unroll
    for (int c = 0; c < 16; ++c) e[c] = p[c];
    const float nrm = np_sumsq64_f4(e);
    norms[row] = nrm;
    uint2* dst = reinterpret_cast<uint2*>(ebuf + (size_t)row * KPAD);
#pragma unroll
    for (int c = 0; c < 16; ++c) {
        uint2 w;
        w.x = f2bf(e[c].x) | (f2bf(e[c].y) << 16);
        w.y = f2bf(e[c].z) | (f2bf(e[c].w) << 16);
        dst[c] = w;
    }
    unsigned int* tail = reinterpret_cast<unsigned int*>(ebuf + (size_t)row * KPAD + DIM);
    tail[0] = f2bf(-0.5f * nrm);
#pragma unroll
    for (int j = 1; j < 8; ++j) tail[j] = 0u;
}

// 5 dependent MFMAs + depth-4 max tree -> OUT = this tile's max (per lane).
#define TILE_MAXV(AF, RT, OUT) do {                                             \
    f32x16 acc_;                                                                \
    _Pragma("unroll") for (int i_ = 0; i_ < 16; ++i_) acc_[i_] = 0.f;           \
    _Pragma("unroll") for (int k_ = 0; k_ < 5; ++k_)                            \
        acc_ = __builtin_amdgcn_mfma_f32_32x32x16_bf16(AF[k_], bfrag[RT][k_],   \
                                                       acc_, 0, 0, 0);          \
    float m0_ = fmaxf(fmaxf(acc_[0], acc_[1]),  fmaxf(acc_[2], acc_[3]));       \
    float m1_ = fmaxf(fmaxf(acc_[4], acc_[5]),  fmaxf(acc_[6], acc_[7]));       \
    float m2_ = fmaxf(fmaxf(acc_[8], acc_[9]),  fmaxf(acc_[10], acc_[11]));     \
    float m3_ = fmaxf(fmaxf(acc_[12], acc_[13]), fmaxf(acc_[14], acc_[15]));    \
    OUT = fmaxf(fmaxf(m0_, m1_), fmaxf(m2_, m3_));                              \
} while (0)

__global__ __launch_bounds__(512, 4)
void vq_fused_kernel(const unsigned short* __restrict__ ebuf,
                     const float* __restrict__ x, const float* __restrict__ cb,
                     const float* __restrict__ norms,
                     float* __restrict__ out_q, float* __restrict__ out_idx,
                     float* __restrict__ block_loss) {
    const int tid  = threadIdx.x;
    const int lane = tid & 63;
    const int wid  = tid >> 6;          // 0..7: candidate split
    const int half = lane >> 5;
    const int l31  = lane & 31;
    const int rowbase  = blockIdx.x * ROWS_PB;
    const int candbase = wid * 1024;

    __shared__ float stmax[WAVES][NT / 2][ROWS_PB];   // 32 KB
    __shared__ float sm[WAVES][ROWS_PB];              // 2 KB
    __shared__ float sthr[ROWS_PB];
    __shared__ int   scnt[ROWS_PB];
    __shared__ int   stiles[ROWS_PB][CAP_T];          // 4 KB
    __shared__ float wloss[WAVES];

    if (tid < ROWS_PB) scnt[tid] = 0;

    // ---- B fragments built in-kernel from x (bit-identical f2bf packing) ----
    // lane l31 holds row (rowbase + rt*32 + l31), K-slice [ks*16+half*8, +8)
    bf16x8 bfrag[2][5];
#pragma unroll
    for (int rt = 0; rt < 2; ++rt) {
        const float* xrow = x + (size_t)(rowbase + rt * 32 + l31) * DIM;
#pragma unroll
        for (int ks = 0; ks < 4; ++ks) {
            const float4* p = reinterpret_cast<const float4*>(xrow + ks * 16 + half * 8);
            float4 v0 = p[0], v1 = p[1];
            bf16x8 f;
            f[0] = (short)f2bf(v0.x); f[1] = (short)f2bf(v0.y);
            f[2] = (short)f2bf(v0.z); f[3] = (short)f2bf(v0.w);
            f[4] = (short)f2bf(v1.x); f[5] = (short)f2bf(v1.y);
            f[6] = (short)f2bf(v1.z); f[7] = (short)f2bf(v1.w);
            bfrag[rt][ks] = f;
        }
        // K = [64,80): padded x tail = [1.0, 0 x15]
        bf16x8 ft;
#pragma unroll
        for (int j = 0; j < 8; ++j) ft[j] = 0;
        if (half == 0) ft[0] = (short)0x3F80;   // bf16(1.0)
        bfrag[rt][4] = ft;
    }

    const unsigned short* abase = ebuf + (size_t)(candbase + l31) * KPAD + half * 8;

    // ---- single MFMA pass: per-(row, tile-pair) max into LDS ----
    bf16x8 a0[5], a1[5];
#pragma unroll
    for (int ks = 0; ks < 5; ++ks)
        a0[ks] = *reinterpret_cast<const bf16x8*>(abase + ks * 16);

    for (int t = 0; t < NT; t += 2) {
        const unsigned short* ap1 = abase + (size_t)(t + 1) * 32 * KPAD;
#pragma unroll
        for (int ks = 0; ks < 5; ++ks)
            a1[ks] = *reinterpret_cast<const bf16x8*>(ap1 + ks * 16);
        float m00, m01;
        TILE_MAXV(a0, 0, m00);
        TILE_MAXV(a0, 1, m01);
        // prefetch t+2 (masked at the end to avoid OOB read past ebuf)
        const unsigned short* ap2 = abase + (size_t)((t + 2) & (NT - 1)) * 32 * KPAD;
#pragma unroll
        for (int ks = 0; ks < 5; ++ks)
            a0[ks] = *reinterpret_cast<const bf16x8*>(ap2 + ks * 16);
        float m10, m11;
        TILE_MAXV(a1, 0, m10);
        TILE_MAXV(a1, 1, m11);
        float p0 = fmaxf(m00, m10);              // pair max, rt 0
        float p1 = fmaxf(m01, m11);              // pair max, rt 1
        p0 = fmaxf(p0, __shfl_xor(p0, 32));      // merge k-halves' cand sets
        p1 = fmaxf(p1, __shfl_xor(p1, 32));
        if (half == 0) stmax[wid][t >> 1][l31]      = p0;
        else           stmax[wid][t >> 1][32 + l31] = p1;
    }
    __syncthreads();

    // ---- block max fold -> per-row threshold ----
    {
        const int w = tid >> 6, r = tid & 63;
        float m = stmax[w][0][r];
#pragma unroll
        for (int tp = 1; tp < NT / 2; ++tp) m = fmaxf(m, stmax[w][tp][r]);
        sm[w][r] = m;
    }
    __syncthreads();
    if (tid < ROWS_PB) {
        float m = sm[0][tid];
#pragma unroll
        for (int w = 1; w < WAVES; ++w) m = fmaxf(m, sm[w][tid]);
        sthr[tid] = m - TMARGIN;
    }
    __syncthreads();

    // ---- build per-row hot tile-pair lists ----
    for (int e = tid; e < WAVES * (NT / 2) * ROWS_PB; e += 512) {
        const int w = e >> 10, tp = (e >> 6) & (NT / 2 - 1), r = e & 63;
        if (stmax[w][tp][r] >= sthr[r]) {
            const int pos = atomicAdd(&scnt[r], 1);
            if (pos < CAP_T) stiles[r][pos] = w * (NT / 2) + tp;
        }
    }
    __syncthreads();

    // ---- finalize: wave handles 8 rows; exact rescore + gather + loss ----
    float lsum = 0.f;
    for (int i = 0; i < 8; ++i) {
        const int lr = wid * 8 + i;
        const int r  = rowbase + lr;
        const int c0 = scnt[lr];
        const bool okc = (c0 <= CAP_T);
        const int ncand = okc ? c0 * 64 : NUM_E;   // overflow -> full scan
        float4 xr[16];
        const float4* xp = reinterpret_cast<const float4*>(x + (size_t)r * DIM);
#pragma unroll
        for (int c = 0; c < 16; ++c) xr[c] = xp[c];
        const float sx = np_sumsq64_f4(xr);        // identical fn -> bit-identical
        float best = FLTMAX;
        int bi = 0x7FFFFFFF;
        for (int j = lane; j < ncand; j += 64) {
            const int k = okc ? (stiles[lr][j >> 6] * 64 + (j & 63)) : j;
            const float* ep = cb + (size_t)k * DIM;
            float dot = 0.f;   // sequential fmaf chain d=0..63 (exact replication)
#pragma unroll
            for (int c = 0; c < 16; ++c) {
                dot = fmaf(xr[c].x, ep[4 * c + 0], dot);
                dot = fmaf(xr[c].y, ep[4 * c + 1], dot);
                dot = fmaf(xr[c].z, ep[4 * c + 2], dot);
                dot = fmaf(xr[c].w, ep[4 * c + 3], dot);
            }
            const float t1 = __fadd_rn(sx, norms[k]);
            const float d2 = __fadd_rn(dot, dot);
            const float sc = __fsub_rn(t1, d2);
            if (sc < best || (sc == best && k < bi)) { best = sc; bi = k; }
        }
#pragma unroll
        for (int off = 1; off < 64; off <<= 1) {   // lexicographic first-min
            const float s2 = __shfl_xor(best, off);
            const int   i2 = __shfl_xor(bi, off);
            if (s2 < best || (s2 == best && i2 < bi)) { best = s2; bi = i2; }
        }
        const float ed = cb[(size_t)bi * DIM + lane];
        const float xd = x[(size_t)r * DIM + lane];
        out_q[(size_t)r * DIM + lane] = ed;
        if (lane == 0) out_idx[r] = (float)bi;
        const float dd = ed - xd;
        lsum = fmaf(dd, dd, lsum);
    }
#pragma unroll
    for (int off = 1; off < 64; off <<= 1) lsum += __shfl_xor(lsum, off);
    if (lane == 0) wloss[wid] = lsum;
    __syncthreads();
    if (tid == 0) {
        float s = 0.f;
#pragma unroll
        for (int w = 0; w < WAVES; ++w) s += wloss[w];
        block_loss[blockIdx.x] = s;
    }
}

__global__ __launch_bounds__(256)
void vq_loss_kernel(const float* __restrict__ block_loss,
                    float* __restrict__ out_loss) {
    float s = 0.f;
    for (int i = threadIdx.x; i < NROWS / ROWS_PB; i += 256) s += block_loss[i];
#pragma unroll
    for (int off = 1; off < 64; off <<= 1) s += __shfl_xor(s, off);
    __shared__ float wsum[4];
    const int lane = threadIdx.x & 63, wv = threadIdx.x >> 6;
    if (lane == 0) wsum[wv] = s;
    __syncthreads();
    if (threadIdx.x == 0)
        *out_loss = ((wsum[0] + wsum[1]) + (wsum[2] + wsum[3])) * (1.25f / (float)NELEM);
}

extern "C" void kernel_launch(void* const* d_in, const int* in_sizes, int n_in,
                              void* d_out, int out_size, void* d_ws, size_t ws_size,
                              hipStream_t stream) {
    const float* x  = (const float*)d_in[0];
    const float* cb = (const float*)d_in[1];

    float* out_q    = (float*)d_out;
    float* out_loss = (float*)d_out + NELEM;
    float* out_idx  = (float*)d_out + NELEM + 1;

    float* wsf        = (float*)d_ws;
    float* block_loss = wsf;                              // 512
    float* norms      = wsf + 512;                        // 8192
    unsigned short* ebuf = (unsigned short*)(norms + NUM_E);  // 8192*80 bf16

    vq_prep_cb<<<NUM_E / 256, 256, 0, stream>>>(cb, norms, ebuf);
    vq_fused_kernel<<<NROWS / ROWS_PB, 512, 0, stream>>>(ebuf, x, cb, norms,
                                                         out_q, out_idx, block_loss);
    vq_loss_kernel<<<1, 256, 0, stream>>>(block_loss, out_loss);
}

// Round 9
// 190.263 us; speedup vs baseline: 5.0069x; 5.0069x over previous
//
#include <hip/hip_runtime.h>

// VectorQuantizer on MI355X — round 9: single-pass max + hot-pair-pruned
// per-candidate gather + fused loss.
// x: [32768, 64] f32, codebook: [8192, 64] f32.
// out (f32): [0..2097152) quantized, [2097152] loss, [2097153..) indices as floats.
//
// Block = 512 thr (8 waves) x 64 rows; wave w covers cands [w*1024,+1024) as
// 32 tiles of 32 (16 tile-pairs).
// Pass 1: per-(row, tile-pair) max of t_k = x.e_k - ||e_k||^2/2 into LDS.
// Thresholds (max - 1.5e-4; statistical bf16 error ~1.2e-6 RMS, >100x slack),
// then per-wave hot-pair bitmask (hot iff any of the 64 rows within margin).
// Pass 2: re-MFMA ONLY hot pairs (~60%), gather exact candidate indices
// (r7-validated path) into LDS shortlist (~2 cands/row).
// Finalize: wave-per-8-rows EXACT rescore (round-2-validated numpy numerics,
// first-min tie rule, float4 loads in identical fmaf order) + gather + loss
// (one f32 atomicAdd per block; tolerance 2%). Overflow -> wave-parallel scan.

#define NUM_E   8192
#define DIM     64
#define KPAD    80
#define NROWS   32768
#define NELEM   2097152
#define CAP     32
#define TMARGIN 1.5e-4f
#define ROWS_PB 64
#define WAVES   8
#define NT      32          // tiles of 32 cands per wave
#define FLTMAX  3.402823466e+38f

using bf16x8 = __attribute__((ext_vector_type(8))) short;
using f32x16 = __attribute__((ext_vector_type(16))) float;

__device__ __forceinline__ unsigned int f2bf(float f) {
    unsigned int u = __float_as_uint(f);
    return (u + 0x7FFFu + ((u >> 16) & 1u)) >> 16;   // RNE to bf16
}

// numpy pairwise_sum(n=64) of elementwise squares (validated bit-exact r2+).
__device__ __forceinline__ float np_sumsq64_f4(const float4 v[16]) {
    float r0 = __fmul_rn(v[0].x, v[0].x), r1 = __fmul_rn(v[0].y, v[0].y);
    float r2 = __fmul_rn(v[0].z, v[0].z), r3 = __fmul_rn(v[0].w, v[0].w);
    float r4 = __fmul_rn(v[1].x, v[1].x), r5 = __fmul_rn(v[1].y, v[1].y);
    float r6 = __fmul_rn(v[1].z, v[1].z), r7 = __fmul_rn(v[1].w, v[1].w);
#pragma unroll
    for (int t = 1; t < 8; ++t) {
        r0 = __fadd_rn(r0, __fmul_rn(v[2 * t].x, v[2 * t].x));
        r1 = __fadd_rn(r1, __fmul_rn(v[2 * t].y, v[2 * t].y));
        r2 = __fadd_rn(r2, __fmul_rn(v[2 * t].z, v[2 * t].z));
        r3 = __fadd_rn(r3, __fmul_rn(v[2 * t].w, v[2 * t].w));
        r4 = __fadd_rn(r4, __fmul_rn(v[2 * t + 1].x, v[2 * t + 1].x));
        r5 = __fadd_rn(r5, __fmul_rn(v[2 * t + 1].y, v[2 * t + 1].y));
        r6 = __fadd_rn(r6, __fmul_rn(v[2 * t + 1].z, v[2 * t + 1].z));
        r7 = __fadd_rn(r7, __fmul_rn(v[2 * t + 1].w, v[2 * t + 1].w));
    }
    return __fadd_rn(__fadd_rn(__fadd_rn(r0, r1), __fadd_rn(r2, r3)),
                     __fadd_rn(__fadd_rn(r4, r5), __fadd_rn(r6, r7)));
}

__global__ __launch_bounds__(256)
void vq_prep_cb(const float* __restrict__ cb, float* __restrict__ norms,
                unsigned short* __restrict__ ebuf) {
    const int row = blockIdx.x * 256 + threadIdx.x;
    float4 e[16];
    const float4* p = reinterpret_cast<const float4*>(cb + row * DIM);
#pragma unroll
    for (int c = 0; c < 16; ++c) e[c] = p[c];
    const float nrm = np_sumsq64_f4(e);
    norms[row] = nrm;
    uint2* dst = reinterpret_cast<uint2*>(ebuf + (size_t)row * KPAD);
#pragma unroll
    for (int c = 0; c < 16; ++c) {
        uint2 w;
        w.x = f2bf(e[c].x) | (f2bf(e[c].y) << 16);
        w.y = f2bf(e[c].z) | (f2bf(e[c].w) << 16);
        dst[c] = w;
    }
    unsigned int* tail = reinterpret_cast<unsigned int*>(ebuf + (size_t)row * KPAD + DIM);
    tail[0] = f2bf(-0.5f * nrm);
#pragma unroll
    for (int j = 1; j < 8; ++j) tail[j] = 0u;
}

// 5 dependent MFMAs + depth-4 max tree -> OUT = tile max (per lane).
#define TILE_MAXV(AF, RT, OUT) do {                                             \
    f32x16 acc_;                                                                \
    _Pragma("unroll") for (int i_ = 0; i_ < 16; ++i_) acc_[i_] = 0.f;           \
    _Pragma("unroll") for (int k_ = 0; k_ < 5; ++k_)                            \
        acc_ = __builtin_amdgcn_mfma_f32_32x32x16_bf16(AF[k_], bfrag[RT][k_],   \
                                                       acc_, 0, 0, 0);          \
    float m0_ = fmaxf(fmaxf(acc_[0], acc_[1]),  fmaxf(acc_[2], acc_[3]));       \
    float m1_ = fmaxf(fmaxf(acc_[4], acc_[5]),  fmaxf(acc_[6], acc_[7]));       \
    float m2_ = fmaxf(fmaxf(acc_[8], acc_[9]),  fmaxf(acc_[10], acc_[11]));     \
    float m3_ = fmaxf(fmaxf(acc_[12], acc_[13]), fmaxf(acc_[14], acc_[15]));    \
    OUT = fmaxf(fmaxf(m0_, m1_), fmaxf(m2_, m3_));                              \
} while (0)

// Recompute (bit-identical) + gather cands above per-row threshold into LDS.
#define TILE_GATHER(AF, RT, THR, TIDX) do {                                     \
    f32x16 acc_;                                                                \
    _Pragma("unroll") for (int i_ = 0; i_ < 16; ++i_) acc_[i_] = 0.f;           \
    _Pragma("unroll") for (int k_ = 0; k_ < 5; ++k_)                            \
        acc_ = __builtin_amdgcn_mfma_f32_32x32x16_bf16(AF[k_], bfrag[RT][k_],   \
                                                       acc_, 0, 0, 0);          \
    float m0_ = fmaxf(fmaxf(acc_[0], acc_[1]),  fmaxf(acc_[2], acc_[3]));       \
    float m1_ = fmaxf(fmaxf(acc_[4], acc_[5]),  fmaxf(acc_[6], acc_[7]));       \
    float m2_ = fmaxf(fmaxf(acc_[8], acc_[9]),  fmaxf(acc_[10], acc_[11]));     \
    float m3_ = fmaxf(fmaxf(acc_[12], acc_[13]), fmaxf(acc_[14], acc_[15]));    \
    float tm_ = fmaxf(fmaxf(m0_, m1_), fmaxf(m2_, m3_));                        \
    if (__any(tm_ >= (THR))) {                                                  \
        const int lr_ = (RT) * 32 + l31;                                        \
        _Pragma("unroll") for (int r_ = 0; r_ < 16; ++r_) {                     \
            if (acc_[r_] >= (THR)) {                                            \
                const int crow_ = (r_ & 3) + 8 * (r_ >> 2) + 4 * half;          \
                const int pos_ = atomicAdd(&scnt[lr_], 1);                      \
                if (pos_ < CAP)                                                 \
                    sslots[lr_][pos_] = candbase + (TIDX) * 32 + crow_;         \
            }                                                                   \
        }                                                                       \
    }                                                                           \
} while (0)

__global__ __launch_bounds__(512, 4)
void vq_fused_kernel(const unsigned short* __restrict__ ebuf,
                     const float* __restrict__ x, const float* __restrict__ cb,
                     const float* __restrict__ norms,
                     float* __restrict__ out_q, float* __restrict__ out_idx,
                     float* __restrict__ out_loss) {
    const int tid  = threadIdx.x;
    const int lane = tid & 63;
    const int wid  = tid >> 6;          // 0..7: candidate split
    const int half = lane >> 5;
    const int l31  = lane & 31;
    const int rowbase  = blockIdx.x * ROWS_PB;
    const int candbase = wid * 1024;

    __shared__ float stmax[WAVES][NT / 2][ROWS_PB];   // 32 KB
    __shared__ float sm[WAVES][ROWS_PB];              // 2 KB
    __shared__ float sthr[ROWS_PB];
    __shared__ int   scnt[ROWS_PB];
    __shared__ unsigned int shot[WAVES];              // hot tile-pair bitmasks
    __shared__ int   sslots[ROWS_PB][CAP];            // 8 KB
    __shared__ float wloss[WAVES];

    if (tid < ROWS_PB) scnt[tid] = 0;
    if (tid < WAVES)   shot[tid] = 0u;

    // ---- B fragments built in-kernel from x (bit-identical f2bf packing) ----
    bf16x8 bfrag[2][5];
#pragma unroll
    for (int rt = 0; rt < 2; ++rt) {
        const float* xrow = x + (size_t)(rowbase + rt * 32 + l31) * DIM;
#pragma unroll
        for (int ks = 0; ks < 4; ++ks) {
            const float4* p = reinterpret_cast<const float4*>(xrow + ks * 16 + half * 8);
            float4 v0 = p[0], v1 = p[1];
            bf16x8 f;
            f[0] = (short)f2bf(v0.x); f[1] = (short)f2bf(v0.y);
            f[2] = (short)f2bf(v0.z); f[3] = (short)f2bf(v0.w);
            f[4] = (short)f2bf(v1.x); f[5] = (short)f2bf(v1.y);
            f[6] = (short)f2bf(v1.z); f[7] = (short)f2bf(v1.w);
            bfrag[rt][ks] = f;
        }
        bf16x8 ft;   // K = [64,80): padded x tail = [1.0, 0 x15]
#pragma unroll
        for (int j = 0; j < 8; ++j) ft[j] = 0;
        if (half == 0) ft[0] = (short)0x3F80;   // bf16(1.0)
        bfrag[rt][4] = ft;
    }

    const unsigned short* abase = ebuf + (size_t)(candbase + l31) * KPAD + half * 8;

    // ---- pass 1: per-(row, tile-pair) max into LDS, 2-deep A prefetch ----
    bf16x8 a0[5], a1[5];
#pragma unroll
    for (int ks = 0; ks < 5; ++ks)
        a0[ks] = *reinterpret_cast<const bf16x8*>(abase + ks * 16);

    for (int t = 0; t < NT; t += 2) {
        const unsigned short* ap1 = abase + (size_t)(t + 1) * 32 * KPAD;
#pragma unroll
        for (int ks = 0; ks < 5; ++ks)
            a1[ks] = *reinterpret_cast<const bf16x8*>(ap1 + ks * 16);
        float m00, m01;
        TILE_MAXV(a0, 0, m00);
        TILE_MAXV(a0, 1, m01);
        const unsigned short* ap2 = abase + (size_t)((t + 2) & (NT - 1)) * 32 * KPAD;
#pragma unroll
        for (int ks = 0; ks < 5; ++ks)
            a0[ks] = *reinterpret_cast<const bf16x8*>(ap2 + ks * 16);
        float m10, m11;
        TILE_MAXV(a1, 0, m10);
        TILE_MAXV(a1, 1, m11);
        float p0 = fmaxf(m00, m10);
        float p1 = fmaxf(m01, m11);
        p0 = fmaxf(p0, __shfl_xor(p0, 32));      // merge cand-halves per row
        p1 = fmaxf(p1, __shfl_xor(p1, 32));
        if (half == 0) stmax[wid][t >> 1][l31]      = p0;
        else           stmax[wid][t >> 1][32 + l31] = p1;
    }
    __syncthreads();

    // ---- block max fold -> per-row threshold ----
    {
        const int w = tid >> 6, r = tid & 63;
        float m = stmax[w][0][r];
#pragma unroll
        for (int tp = 1; tp < NT / 2; ++tp) m = fmaxf(m, stmax[w][tp][r]);
        sm[w][r] = m;
    }
    __syncthreads();
    if (tid < ROWS_PB) {
        float m = sm[0][tid];
#pragma unroll
        for (int w = 1; w < WAVES; ++w) m = fmaxf(m, sm[w][tid]);
        sthr[tid] = m - TMARGIN;
    }
    __syncthreads();

    // ---- hot-pair bitmask: pair hot iff any of the 64 rows within margin ----
    {
        const int pair = tid >> 2, sub = tid & 3;   // 128 pairs x 4 sub-scans
        const int w = pair >> 4, tp = pair & 15;
        bool hot = false;
        for (int r = sub * 16; r < sub * 16 + 16; ++r)
            hot = hot || (stmax[w][tp][r] >= sthr[r]);
        if (hot) atomicOr(&shot[w], 1u << tp);
    }
    __syncthreads();

    // ---- pass 2: re-MFMA only hot pairs, per-candidate gather ----
    {
        const float thr0 = sthr[l31];
        const float thr1 = sthr[32 + l31];
        unsigned int mask = shot[wid];
        while (mask) {
            const int tp = __ffs(mask) - 1;
            mask &= mask - 1;
            const int t0 = 2 * tp;
            const unsigned short* ap0 = abase + (size_t)t0 * 32 * KPAD;
            const unsigned short* ap1 = abase + (size_t)(t0 + 1) * 32 * KPAD;
#pragma unroll
            for (int ks = 0; ks < 5; ++ks) {
                a0[ks] = *reinterpret_cast<const bf16x8*>(ap0 + ks * 16);
                a1[ks] = *reinterpret_cast<const bf16x8*>(ap1 + ks * 16);
            }
            TILE_GATHER(a0, 0, thr0, t0);
            TILE_GATHER(a0, 1, thr1, t0);
            TILE_GATHER(a1, 0, thr0, t0 + 1);
            TILE_GATHER(a1, 1, thr1, t0 + 1);
        }
    }
    __syncthreads();

    // ---- finalize: wave per 8 rows; exact rescore + gather + loss ----
    float lsum = 0.f;
    for (int i = 0; i < 8; ++i) {
        const int lr = wid * 8 + i;
        const int r  = rowbase + lr;
        const int c0 = scnt[lr];
        const bool okc = (c0 <= CAP);
        const int ncand = okc ? c0 : NUM_E;   // overflow -> wave-parallel scan
        float4 xr[16];
        const float4* xp = reinterpret_cast<const float4*>(x + (size_t)r * DIM);
#pragma unroll
        for (int c = 0; c < 16; ++c) xr[c] = xp[c];
        const float sx = np_sumsq64_f4(xr);   // identical fn -> bit-identical
        float best = FLTMAX;
        int bi = 0x7FFFFFFF;
        for (int j = lane; j < ncand; j += 64) {
            const int k = okc ? sslots[lr][j] : j;
            const float4* ep4 = reinterpret_cast<const float4*>(cb + (size_t)k * DIM);
            float dot = 0.f;   // sequential fmaf chain d=0..63 (exact replication)
#pragma unroll
            for (int c = 0; c < 16; c += 4) {
                float4 e0 = ep4[c], e1 = ep4[c + 1], e2 = ep4[c + 2], e3 = ep4[c + 3];
                dot = fmaf(xr[c].x,     e0.x, dot); dot = fmaf(xr[c].y,     e0.y, dot);
                dot = fmaf(xr[c].z,     e0.z, dot); dot = fmaf(xr[c].w,     e0.w, dot);
                dot = fmaf(xr[c + 1].x, e1.x, dot); dot = fmaf(xr[c + 1].y, e1.y, dot);
                dot = fmaf(xr[c + 1].z, e1.z, dot); dot = fmaf(xr[c + 1].w, e1.w, dot);
                dot = fmaf(xr[c + 2].x, e2.x, dot); dot = fmaf(xr[c + 2].y, e2.y, dot);
                dot = fmaf(xr[c + 2].z, e2.z, dot); dot = fmaf(xr[c + 2].w, e2.w, dot);
                dot = fmaf(xr[c + 3].x, e3.x, dot); dot = fmaf(xr[c + 3].y, e3.y, dot);
                dot = fmaf(xr[c + 3].z, e3.z, dot); dot = fmaf(xr[c + 3].w, e3.w, dot);
            }
            const float t1 = __fadd_rn(sx, norms[k]);
            const float d2 = __fadd_rn(dot, dot);
            const float sc = __fsub_rn(t1, d2);
            if (sc < best || (sc == best && k < bi)) { best = sc; bi = k; }
        }
#pragma unroll
        for (int off = 1; off < 64; off <<= 1) {   // lexicographic first-min
            const float s2 = __shfl_xor(best, off);
            const int   i2 = __shfl_xor(bi, off);
            if (s2 < best || (s2 == best && i2 < bi)) { best = s2; bi = i2; }
        }
        const float ed = cb[(size_t)bi * DIM + lane];
        const float xd = x[(size_t)r * DIM + lane];
        out_q[(size_t)r * DIM + lane] = ed;
        if (lane == 0) out_idx[r] = (float)bi;
        const float dd = ed - xd;
        lsum = fmaf(dd, dd, lsum);
    }
#pragma unroll
    for (int off = 1; off < 64; off <<= 1) lsum += __shfl_xor(lsum, off);
    if (lane == 0) wloss[wid] = lsum;
    __syncthreads();
    if (tid == 0) {
        float s = 0.f;
#pragma unroll
        for (int w = 0; w < WAVES; ++w) s += wloss[w];
        atomicAdd(out_loss, s * (1.25f / (float)NELEM));
    }
}

extern "C" void kernel_launch(void* const* d_in, const int* in_sizes, int n_in,
                              void* d_out, int out_size, void* d_ws, size_t ws_size,
                              hipStream_t stream) {
    const float* x  = (const float*)d_in[0];
    const float* cb = (const float*)d_in[1];

    float* out_q    = (float*)d_out;
    float* out_loss = (float*)d_out + NELEM;
    float* out_idx  = (float*)d_out + NELEM + 1;

    float* wsf   = (float*)d_ws;
    float* norms = wsf;                                   // 8192
    unsigned short* ebuf = (unsigned short*)(norms + NUM_E);  // 8192*80 bf16

    hipMemsetAsync(out_loss, 0, sizeof(float), stream);   // loss accumulator
    vq_prep_cb<<<NUM_E / 256, 256, 0, stream>>>(cb, norms, ebuf);
    vq_fused_kernel<<<NROWS / ROWS_PB, 512, 0, stream>>>(ebuf, x, cb, norms,
                                                         out_q, out_idx, out_loss);
}